// Round 16
// baseline (1682.890 us; speedup 1.0000x reference)
//
#include <hip/hip_runtime.h>
#include <hip/hip_bf16.h>

// CharRNN: 2-layer LSTM LM + softmax CE on MI355X (gfx950).
// Round 16: recur_k v3 = r14 shell (folded input projection, 64 merged
// blocks, wide sc0sc1 bulk loads + masked re-poll) + r11's barrier-free
// quad-shuffle pointwise (K-slot permutation cm=(e>>1)+4*(e&1) on W1r/W2/
// Wvb; leader-lane packed u32 stores; ZERO __syncthreads in the t-loop;
// per-wave decoupled chains). CE v2 (r15) reads permuted h2all/Wvb.
// dims: V=8000, B=64, T=128, H=512.

#define V_SIZE 8000
#define VPAD   8192
#define B_SIZE 64
#define T_SIZE 128
#define H_SIZE 512
#define NG     (4 * H_SIZE)          // 2048 gate columns
#define HB     (H_SIZE * B_SIZE)     // one h time-slice (bf16 elems)
#define RBLK   64                    // recurrence grid (merged blocks)
#define RTH    256                   // recurrence block size
#define SENT   0x7FFF7FFFu

typedef __attribute__((ext_vector_type(8))) short bf16x8;
typedef __attribute__((ext_vector_type(8))) unsigned short u16x8;
typedef __attribute__((ext_vector_type(4))) float f32x4;

// ---------- bf16 helpers (raw ushort storage) ----------
__device__ __forceinline__ float bf2f(unsigned short u) {
  union { unsigned int i; float f; } x; x.i = ((unsigned int)u) << 16; return x.f;
}
__device__ __forceinline__ unsigned short f2bf(float f) {
  union { float f; unsigned int i; } x; x.f = f;
  unsigned int r = x.i + 0x7fffu + ((x.i >> 16) & 1u);
  return (unsigned short)(r >> 16);
}
__device__ __forceinline__ float sigf(float v) { return 1.f / (1.f + __expf(-v)); }
__device__ __forceinline__ float tanhf_fast(float v) {
  return 1.f - 2.f / (__expf(2.f * v) + 1.f);
}

// agent-scope (MALL-coherent) 16B load as 2x u64 atomics (straggler re-poll)
__device__ __forceinline__ bf16x8 aload16(const unsigned short* p) {
  unsigned long long lo = __hip_atomic_load((const unsigned long long*)p,
                                            __ATOMIC_RELAXED, __HIP_MEMORY_SCOPE_AGENT);
  unsigned long long hi = __hip_atomic_load((const unsigned long long*)(p + 4),
                                            __ATOMIC_RELAXED, __HIP_MEMORY_SCOPE_AGENT);
  union { unsigned long long v[2]; bf16x8 b; } u;
  u.v[0] = lo; u.v[1] = hi;
  return u.b;
}
__device__ __forceinline__ unsigned has_sent(bf16x8 v) {
  union { bf16x8 b; unsigned u[4]; } x; x.b = v;
  return (unsigned)((x.u[0] == SENT) | (x.u[1] == SENT) |
                    (x.u[2] == SENT) | (x.u[3] == SENT));
}

// cache-bypassing (sc0 sc1 -> MALL) 8x16B batch load, one waitcnt.
__device__ __forceinline__ void load8_mall(bf16x8* d, const unsigned short* base) {
  asm volatile(
      "global_load_dwordx4 %0, %8, off sc0 sc1\n\t"
      "global_load_dwordx4 %1, %8, off offset:64 sc0 sc1\n\t"
      "global_load_dwordx4 %2, %8, off offset:128 sc0 sc1\n\t"
      "global_load_dwordx4 %3, %8, off offset:192 sc0 sc1\n\t"
      "global_load_dwordx4 %4, %8, off offset:256 sc0 sc1\n\t"
      "global_load_dwordx4 %5, %8, off offset:320 sc0 sc1\n\t"
      "global_load_dwordx4 %6, %8, off offset:384 sc0 sc1\n\t"
      "global_load_dwordx4 %7, %8, off offset:448 sc0 sc1\n\t"
      "s_waitcnt vmcnt(0)"
      : "=v"(d[0]), "=v"(d[1]), "=v"(d[2]), "=v"(d[3]),
        "=v"(d[4]), "=v"(d[5]), "=v"(d[6]), "=v"(d[7])
      : "v"(base)
      : "memory");
}

// ---------------- fill ----------------
__global__ void fill_k(unsigned* __restrict__ p, unsigned v, int n) {
  int i = blockIdx.x * 256 + threadIdx.x;
  if (i < n) p[i] = v;
}

// ---------------- padded bias: bvp[i] = i<V ? bv[i] : -1e30 ----------------
__global__ void bvp_k(const float* __restrict__ bv, float* __restrict__ bvp) {
  int i = blockIdx.x * 256 + threadIdx.x;   // 8192
  bvp[i] = (i < V_SIZE) ? bv[i] : -1e30f;
}

// ---------------- embedding gather -> bf16 x [8192 rows=t*64+b][512] ----------------
__global__ __launch_bounds__(256) void xgather_k(const int* __restrict__ ids,
                                                 const float* __restrict__ emb,
                                                 unsigned short* __restrict__ xb) {
  int g = blockIdx.x * 256 + threadIdx.x;   // 8192 rows x 64 chunks of 8
  int r = g >> 6, c = g & 63;
  int t = r >> 6, b = r & 63;
  int id = ids[(size_t)b * T_SIZE + t];
  const float4* s4 = reinterpret_cast<const float4*>(emb + (size_t)id * H_SIZE + c * 8);
  float4 v0 = s4[0], v1 = s4[1];
  u16x8 o;
  o[0] = f2bf(v0.x); o[1] = f2bf(v0.y); o[2] = f2bf(v0.z); o[3] = f2bf(v0.w);
  o[4] = f2bf(v1.x); o[5] = f2bf(v1.y); o[6] = f2bf(v1.z); o[7] = f2bf(v1.w);
  *reinterpret_cast<u16x8*>(xb + (size_t)r * H_SIZE + c * 8) = o;
}

// ---------------- f32 [K][N] -> bf16 [Npad][K-permuted] transpose ----------------
// K-slot permutation within each 8-group: slot e holds row (e>>1)+4*(e&1).
// cols >= Nsrc are written as 0.
__global__ __launch_bounds__(256) void trans_k(const float* __restrict__ src,
                                               unsigned short* __restrict__ dst,
                                               int src_ld, int n_tiles, int Nsrc) {
  __shared__ float tile[64][65];
  const int tid = threadIdx.x;
  const int kt = blockIdx.x / n_tiles, nt = blockIdx.x % n_tiles;
#pragma unroll
  for (int q = 0; q < 16; ++q) {
    int f = tid + 256 * q;
    int r = f >> 6, c = f & 63;
    int col = nt * 64 + c;
    tile[r][c] = (col < Nsrc) ? src[(size_t)(kt * 64 + r) * src_ld + col] : 0.f;
  }
  __syncthreads();
#pragma unroll
  for (int q = 0; q < 2; ++q) {
    int u = tid + 256 * q;
    int n = u >> 3, kg = u & 7;
    u16x8 o;
#pragma unroll
    for (int e = 0; e < 8; ++e) {
      int cm = (e >> 1) + 4 * (e & 1);
      o[e] = f2bf(tile[kg * 8 + cm][n]);
    }
    *reinterpret_cast<u16x8*>(dst + (size_t)(nt * 64 + n) * 512 + kt * 64 + kg * 8) = o;
  }
}

// load 8 B-fragments (one K-half) for column vc from a [N][512] bf16 matrix
__device__ __forceinline__ void loadB8(bf16x8* p, const unsigned short* Wb,
                                       int vc, int kh, int kof) {
#pragma unroll
  for (int ks = 0; ks < 8; ++ks)
    p[ks] = *reinterpret_cast<const bf16x8*>(
        Wb + (size_t)vc * 512 + (kh * 8 + ks) * 32 + kof);
}

// ---------------- barrier-free sentinel dataflow 2-layer LSTM ----------------
// 64 blocks; block owns 8 h-cols of BOTH layers. LDS: W1x (32K, unpermuted K)
// + W1r (32K, cm-permuted) + W2 (64K, cm-permuted) = 128 KB. Quad-shuffle
// pointwise, leader-lane stores, NO __syncthreads in the t-loop.
__global__ __launch_bounds__(RTH, 1) void recur_k(
    const float* __restrict__ W1, const float* __restrict__ W2,
    const float* __restrict__ b1f, const float* __restrict__ b2f,
    const unsigned short* __restrict__ xb,
    const unsigned short* __restrict__ hzero,
    unsigned short* __restrict__ h1all, unsigned short* __restrict__ h2all)
{
  __shared__ short wldsX[2 * 16 * 64 * 8];  // 32 KB  W1 x-slice
  __shared__ short wlds1[2 * 16 * 64 * 8];  // 32 KB  W1 h-slice (cm-permuted)
  __shared__ short wlds2[2 * 32 * 64 * 8];  // 64 KB  W2 (cm-permuted)

  const int tid = threadIdx.x;
  const int bid = blockIdx.x;
  const int h0  = bid * 8;
  const int w   = tid >> 6, l = tid & 63;
  const int q   = (l >> 2) & 3;
  const bool leader = (l & 3) == 0;

  // ---- one-time weight preload, bf16 B-frag order ----
  // col(n, ng) = (n&3)*512 + h0 + ng*4 + (n>>2)
  {
    for (int idx = tid; idx < 2 * 16 * 64; idx += RTH) {
      int ln2 = idx & 63;
      int ks  = (idx >> 6) % 16;
      int ng  = (idx >> 6) / 16;
      int n   = ln2 & 15;
      int col = (n & 3) * H_SIZE + h0 + ng * 4 + (n >> 2);
      int kb  = ks * 32 + (ln2 >> 4) * 8;
      short* dX = &wldsX[((size_t)(ng * 16 + ks) * 64 + ln2) * 8];
      short* d1 = &wlds1[((size_t)(ng * 16 + ks) * 64 + ln2) * 8];
#pragma unroll
      for (int e = 0; e < 8; ++e) {
        int cm = (e >> 1) + 4 * (e & 1);
        dX[e] = (short)f2bf(W1[(size_t)(kb + e) * NG + col]);
        d1[e] = (short)f2bf(W1[(size_t)(H_SIZE + kb + cm) * NG + col]);
      }
    }
    for (int idx = tid; idx < 2 * 32 * 64; idx += RTH) {
      int ln2 = idx & 63;
      int ks  = (idx >> 6) % 32;
      int ng  = (idx >> 6) / 32;
      int n   = ln2 & 15;
      int col = (n & 3) * H_SIZE + h0 + ng * 4 + (n >> 2);
      int kb  = ks * 32 + (ln2 >> 4) * 8;
      short* dst = &wlds2[((size_t)(ng * 32 + ks) * 64 + ln2) * 8];
#pragma unroll
      for (int e = 0; e < 8; ++e) {
        int cm = (e >> 1) + 4 * (e & 1);
        dst[e] = (short)f2bf(W2[(size_t)(kb + cm) * NG + col]);
      }
    }
  }

  float bA1[4], bB1[4], bA2[4], bB2[4];
#pragma unroll
  for (int g = 0; g < 4; ++g) {
    bA1[g] = b1f[g * H_SIZE + h0 + q];
    bB1[g] = b1f[g * H_SIZE + h0 + q + 4];
    bA2[g] = b2f[g * H_SIZE + h0 + q];
    bB2[g] = b2f[g * H_SIZE + h0 + q + 4];
  }
  float c1a[4] = {0,0,0,0}, c1b[4] = {0,0,0,0};
  float c2a[4] = {0,0,0,0}, c2b[4] = {0,0,0,0};
  __syncthreads();   // weights ready (only barrier in the kernel)

  const int arow = w * 16 + (l & 15);
  const int kof  = (l >> 4) * 8;

  for (int t = 0; t <= T_SIZE; ++t) {
    // ---- x-part of L1(t): independent of h -> fills the wait window ----
    f32x4 acc0 = {0.f, 0.f, 0.f, 0.f};
    f32x4 acc1 = {0.f, 0.f, 0.f, 0.f};
    if (t < T_SIZE) {
      const unsigned short* xr = xb + ((size_t)t * 64 + arow) * H_SIZE + kof;
#pragma unroll
      for (int ks = 0; ks < 16; ++ks) {
        bf16x8 avx = *reinterpret_cast<const bf16x8*>(xr + ks * 32);
        bf16x8 bv0 = *reinterpret_cast<const bf16x8*>(&wldsX[((size_t)(0 * 16 + ks) * 64 + l) * 8]);
        bf16x8 bv1 = *reinterpret_cast<const bf16x8*>(&wldsX[((size_t)(1 * 16 + ks) * 64 + l) * 8]);
        acc0 = __builtin_amdgcn_mfma_f32_16x16x32_bf16(avx, bv0, acc0, 0, 0, 0);
        acc1 = __builtin_amdgcn_mfma_f32_16x16x32_bf16(avx, bv1, acc1, 0, 0, 0);
      }
    }

    // ---- wide bulk load of h1[t-1], h2[t-2] + masked per-chunk re-poll ----
    const unsigned short* h1src = ((t == 0) ? hzero : h1all + (size_t)(t - 1) * HB)
                                  + (size_t)arow * H_SIZE + kof;
    const unsigned short* h2src = ((t < 2) ? hzero : h2all + (size_t)(t - 2) * HB)
                                  + (size_t)arow * H_SIZE + kof;
    bf16x8 av1[16], av2[16];
    load8_mall(av1, h1src);
    load8_mall(av1 + 8, h1src + 256);
    load8_mall(av2, h2src);
    load8_mall(av2 + 8, h2src + 256);
    {
      unsigned p1m = 0, p2m = 0;
#pragma unroll
      for (int ks = 0; ks < 16; ++ks) {
        p1m |= has_sent(av1[ks]) << ks;
        p2m |= has_sent(av2[ks]) << ks;
      }
      while (p1m | p2m) {
        __builtin_amdgcn_s_sleep(2);
#pragma unroll
        for (int ks = 0; ks < 16; ++ks)
          if ((p1m >> ks) & 1) {
            av1[ks] = aload16(h1src + ks * 32);
            if (!has_sent(av1[ks])) p1m &= ~(1u << ks);
          }
#pragma unroll
        for (int ks = 0; ks < 16; ++ks)
          if ((p2m >> ks) & 1) {
            av2[ks] = aload16(h2src + ks * 32);
            if (!has_sent(av2[ks])) p2m &= ~(1u << ks);
          }
      }
    }

    // ================= L1(t): h-MFMA + quad-shuffle pointwise + store =================
    if (t < T_SIZE) {
#pragma unroll
      for (int ks = 0; ks < 16; ++ks) {
        bf16x8 bv0 = *reinterpret_cast<const bf16x8*>(&wlds1[((size_t)(0 * 16 + ks) * 64 + l) * 8]);
        bf16x8 bv1 = *reinterpret_cast<const bf16x8*>(&wlds1[((size_t)(1 * 16 + ks) * 64 + l) * 8]);
        acc0 = __builtin_amdgcn_mfma_f32_16x16x32_bf16(av1[ks], bv0, acc0, 0, 0, 0);
        acc1 = __builtin_amdgcn_mfma_f32_16x16x32_bf16(av1[ks], bv1, acc1, 0, 0, 0);
      }
      unsigned pk[4];
#pragma unroll
      for (int r = 0; r < 4; ++r) {
        float aj = __shfl_xor(acc0[r], 1, 64);
        float af = __shfl_xor(acc0[r], 2, 64);
        float ao = __shfl_xor(acc0[r], 3, 64);
        float bj = __shfl_xor(acc1[r], 1, 64);
        float bfv = __shfl_xor(acc1[r], 2, 64);
        float bo = __shfl_xor(acc1[r], 3, 64);
        float ia = sigf(acc0[r] + bA1[0]);
        float ja = tanhf_fast(aj + bA1[1]);
        float fa = sigf(af + bA1[2]);
        float oa = sigf(ao + bA1[3]);
        float cna = c1a[r] * fa + ia * ja; c1a[r] = cna;
        float ha = tanhf_fast(cna) * oa;
        float ib = sigf(acc1[r] + bB1[0]);
        float jb = tanhf_fast(bj + bB1[1]);
        float fb = sigf(bfv + bB1[2]);
        float ob = sigf(bo + bB1[3]);
        float cnb = c1b[r] * fb + ib * jb; c1b[r] = cnb;
        float hb = tanhf_fast(cnb) * ob;
        pk[r] = (unsigned)f2bf(ha) | ((unsigned)f2bf(hb) << 16);
      }
      if (leader) {
#pragma unroll
        for (int r = 0; r < 4; ++r) {
          unsigned* dst = (unsigned*)(h1all + (size_t)t * HB
                          + (size_t)(w * 16 + (l >> 4) * 4 + r) * H_SIZE + h0 + 2 * q);
          __hip_atomic_store(dst, pk[r], __ATOMIC_RELAXED, __HIP_MEMORY_SCOPE_AGENT);
        }
      }
    }

    // ================= L2(t-1): MFMA + quad-shuffle pointwise + store =================
    if (t >= 1) {
      f32x4 bcc0 = {0.f, 0.f, 0.f, 0.f};
      f32x4 bcc1 = {0.f, 0.f, 0.f, 0.f};
#pragma unroll
      for (int ks = 0; ks < 16; ++ks) {   // h2[t-2] x W2 rows 512..1023
        bf16x8 bv0 = *reinterpret_cast<const bf16x8*>(&wlds2[((size_t)(0 * 32 + 16 + ks) * 64 + l) * 8]);
        bf16x8 bv1 = *reinterpret_cast<const bf16x8*>(&wlds2[((size_t)(1 * 32 + 16 + ks) * 64 + l) * 8]);
        bcc0 = __builtin_amdgcn_mfma_f32_16x16x32_bf16(av2[ks], bv0, bcc0, 0, 0, 0);
        bcc1 = __builtin_amdgcn_mfma_f32_16x16x32_bf16(av2[ks], bv1, bcc1, 0, 0, 0);
      }
#pragma unroll
      for (int ks = 0; ks < 16; ++ks) {   // h1[t-1] x W2 rows 0..511
        bf16x8 bv0 = *reinterpret_cast<const bf16x8*>(&wlds2[((size_t)(0 * 32 + ks) * 64 + l) * 8]);
        bf16x8 bv1 = *reinterpret_cast<const bf16x8*>(&wlds2[((size_t)(1 * 32 + ks) * 64 + l) * 8]);
        bcc0 = __builtin_amdgcn_mfma_f32_16x16x32_bf16(av1[ks], bv0, bcc0, 0, 0, 0);
        bcc1 = __builtin_amdgcn_mfma_f32_16x16x32_bf16(av1[ks], bv1, bcc1, 0, 0, 0);
      }
      unsigned pk[4];
#pragma unroll
      for (int r = 0; r < 4; ++r) {
        float aj = __shfl_xor(bcc0[r], 1, 64);
        float af = __shfl_xor(bcc0[r], 2, 64);
        float ao = __shfl_xor(bcc0[r], 3, 64);
        float bj = __shfl_xor(bcc1[r], 1, 64);
        float bfv = __shfl_xor(bcc1[r], 2, 64);
        float bo = __shfl_xor(bcc1[r], 3, 64);
        float ia = sigf(bcc0[r] + bA2[0]);
        float ja = tanhf_fast(aj + bA2[1]);
        float fa = sigf(af + bA2[2]);
        float oa = sigf(ao + bA2[3]);
        float cna = c2a[r] * fa + ia * ja; c2a[r] = cna;
        float ha = tanhf_fast(cna) * oa;
        float ib = sigf(bcc1[r] + bB2[0]);
        float jb = tanhf_fast(bj + bB2[1]);
        float fb = sigf(bfv + bB2[2]);
        float ob = sigf(bo + bB2[3]);
        float cnb = c2b[r] * fb + ib * jb; c2b[r] = cnb;
        float hb = tanhf_fast(cnb) * ob;
        pk[r] = (unsigned)f2bf(ha) | ((unsigned)f2bf(hb) << 16);
      }
      if (leader) {
#pragma unroll
        for (int r = 0; r < 4; ++r) {
          unsigned* dst = (unsigned*)(h2all + (size_t)(t - 1) * HB
                          + (size_t)(w * 16 + (l >> 4) * 4 + r) * H_SIZE + h0 + 2 * q);
          __hip_atomic_store(dst, pk[r], __ATOMIC_RELAXED, __HIP_MEMORY_SCOPE_AGENT);
        }
      }
    }
  }
}

// ---------------- CE v2: 256 rows x 1024 cols per block, no-max lse ----------------
// grid 256 = 32 row-blocks x 8 col-strips; 512 threads (8 waves share cols).
__global__ __launch_bounds__(512) void ce2_k(const unsigned short* __restrict__ outs,
                                             const unsigned short* __restrict__ Wvb,
                                             const float* __restrict__ bvp,
                                             const int* __restrict__ tgts,
                                             float* __restrict__ psm,
                                             float* __restrict__ ptg) {
  const int tid = threadIdx.x;
  const int rb = blockIdx.x >> 3, cb = blockIdx.x & 7;
  const int w = tid >> 6, l = tid & 63;
  const int kof = (l >> 4) * 8;
  const int ln = l & 15;
  const int r0 = rb * 256 + w * 32;
  const int cbase = cb * 1024;

  bf16x8 av0[16], av1[16];
#pragma unroll
  for (int ks = 0; ks < 16; ++ks) {
    av0[ks] = *reinterpret_cast<const bf16x8*>(
        outs + (size_t)(r0 + ln) * H_SIZE + ks * 32 + kof);
    av1[ks] = *reinterpret_cast<const bf16x8*>(
        outs + (size_t)(r0 + 16 + ln) * H_SIZE + ks * 32 + kof);
  }
  int lbl0[4], lbl1[4];
#pragma unroll
  for (int r = 0; r < 4; ++r) {
    int rr = r0 + ((l >> 4) << 2) + r;
    lbl0[r] = tgts[(size_t)(rr & 63) * T_SIZE + (rr >> 6)];
    rr += 16;
    lbl1[r] = tgts[(size_t)(rr & 63) * T_SIZE + (rr >> 6)];
  }

  float sm0[4] = {0.f, 0.f, 0.f, 0.f}, sm1[4] = {0.f, 0.f, 0.f, 0.f};
  float tg0[4] = {0.f, 0.f, 0.f, 0.f}, tg1[4] = {0.f, 0.f, 0.f, 0.f};

  bf16x8 p0[8], p1[8];
  loadB8(p0, Wvb, cbase + ln, 0, kof);
  for (int ct = 0; ct < 64; ++ct) {
    const int vc = cbase + ct * 16 + ln;
    const int vcn = cbase + ((ct < 63) ? ct + 1 : ct) * 16 + ln;
    f32x4 a0 = {0.f, 0.f, 0.f, 0.f};
    f32x4 a1 = {0.f, 0.f, 0.f, 0.f};
    loadB8(p1, Wvb, vc, 1, kof);
#pragma unroll
    for (int ks = 0; ks < 8; ++ks) {
      a0 = __builtin_amdgcn_mfma_f32_16x16x32_bf16(av0[ks], p0[ks], a0, 0, 0, 0);
      a1 = __builtin_amdgcn_mfma_f32_16x16x32_bf16(av1[ks], p0[ks], a1, 0, 0, 0);
    }
    loadB8(p0, Wvb, vcn, 0, kof);
#pragma unroll
    for (int ks = 0; ks < 8; ++ks) {
      a0 = __builtin_amdgcn_mfma_f32_16x16x32_bf16(av0[8 + ks], p1[ks], a0, 0, 0, 0);
      a1 = __builtin_amdgcn_mfma_f32_16x16x32_bf16(av1[8 + ks], p1[ks], a1, 0, 0, 0);
    }
    float bb = bvp[vc];
#pragma unroll
    for (int r = 0; r < 4; ++r) {
      float lg = a0[r] + bb;
      sm0[r] += __expf(lg);
      tg0[r] += (vc == lbl0[r]) ? lg : 0.f;
      float lh = a1[r] + bb;
      sm1[r] += __expf(lh);
      tg1[r] += (vc == lbl1[r]) ? lh : 0.f;
    }
  }

#pragma unroll
  for (int off = 1; off <= 8; off <<= 1) {
#pragma unroll
    for (int r = 0; r < 4; ++r) {
      sm0[r] += __shfl_xor(sm0[r], off, 64);
      tg0[r] += __shfl_xor(tg0[r], off, 64);
      sm1[r] += __shfl_xor(sm1[r], off, 64);
      tg1[r] += __shfl_xor(tg1[r], off, 64);
    }
  }
  if (ln == 0) {
    int rrw = r0 + ((l >> 4) << 2);
#pragma unroll
    for (int r = 0; r < 4; ++r) {
      psm[(size_t)cb * 8192 + rrw + r]      = sm0[r];
      ptg[(size_t)cb * 8192 + rrw + r]      = tg0[r];
      psm[(size_t)cb * 8192 + rrw + 16 + r] = sm1[r];
      ptg[(size_t)cb * 8192 + rrw + 16 + r] = tg1[r];
    }
  }
}

// ---------------- merge 8 col-strip partials, per-row loss, sum ----------------
__global__ __launch_bounds__(256) void cemerge_k(const float* __restrict__ psm,
                                                 const float* __restrict__ ptg,
                                                 float* __restrict__ accum) {
  int g = blockIdx.x * 256 + threadIdx.x;   // 0..8191
  float S = 0.f, T = 0.f;
#pragma unroll
  for (int j = 0; j < 8; ++j) {
    S += psm[(size_t)j * 8192 + g];
    T += ptg[(size_t)j * 8192 + g];
  }
  float loss = logf(S) - T;
#pragma unroll
  for (int off = 32; off >= 1; off >>= 1)
    loss += __shfl_xor(loss, off, 64);
  if ((threadIdx.x & 63) == 0) atomicAdd(accum, loss);
}

__global__ void finish_k(const float* __restrict__ accum, float* __restrict__ out) {
  out[0] = accum[0] * (1.f / (float)(B_SIZE * T_SIZE));
}

// ---------------- launcher ----------------
extern "C" void kernel_launch(void* const* d_in, const int* in_sizes, int n_in,
                              void* d_out, int out_size, void* d_ws, size_t ws_size,
                              hipStream_t stream) {
  const int*   ids  = (const int*)  d_in[0];
  const int*   tgts = (const int*)  d_in[1];
  const float* emb  = (const float*)d_in[2];
  const float* W1   = (const float*)d_in[3];
  const float* b1   = (const float*)d_in[4];
  const float* W2   = (const float*)d_in[5];
  const float* b2   = (const float*)d_in[6];
  const float* Wv   = (const float*)d_in[7];
  const float* bv   = (const float*)d_in[8];
  float* out = (float*)d_out;

  // ws layout (bytes), total ~34.2 MB:
  char* ws = (char*)d_ws;
  unsigned short* xb    = (unsigned short*)(ws);                 //  8,388,608
  unsigned short* outsb = (unsigned short*)(ws + 8388608);       //  8,388,608 (=h2all)
  unsigned short* h1all = (unsigned short*)(ws + 16777216);      //  8,388,608
  unsigned short* Wvb   = (unsigned short*)(ws + 25165824);      //  8,388,608 (padded 8192x512)
  unsigned short* hzero = (unsigned short*)(ws + 33554432);      //     65,536
  float*          bvp   = (float*)         (ws + 33619968);      //     32,768
  float*          accum = (float*)         (ws + 33652736);      //          4 (pad 64)
  float*          psm   = (float*)         (ws + 33652800);      //    262,144
  float*          ptg   = (float*)         (ws + 33914944);      //    262,144

  // zero hzero + bvp + accum (contiguous 98,368 B = 24,592 u32)
  fill_k<<<97, 256, 0, stream>>>((unsigned*)hzero, 0u, 24592);
  // sentinel-fill outsb + h1all (contiguous 16,777,216 B = 4,194,304 u32)
  fill_k<<<16384, 256, 0, stream>>>((unsigned*)outsb, SENT, 4194304);

  bvp_k<<<32, 256, 0, stream>>>(bv, bvp);
  xgather_k<<<2048, 256, 0, stream>>>(ids, emb, xb);
  trans_k<<<1024, 256, 0, stream>>>(Wv, Wvb, V_SIZE, 128, V_SIZE); // padded + cm-permuted

  {
    void* args[] = { (void*)&W1, (void*)&W2, (void*)&b1, (void*)&b2,
                     (void*)&xb, (void*)&hzero, (void*)&h1all, (void*)&outsb };
    hipError_t e = hipLaunchCooperativeKernel((const void*)recur_k,
                                              dim3(RBLK), dim3(RTH),
                                              args, 0, stream);
    if (e != hipSuccess) {
      recur_k<<<dim3(RBLK), dim3(RTH), 0, stream>>>(W1, W2, b1, b2, xb, hzero,
                                                    h1all, outsb);
    }
  }

  ce2_k<<<256, 512, 0, stream>>>(outsb, Wvb, bvp, tgts, psm, ptg);
  cemerge_k<<<32, 256, 0, stream>>>(psm, ptg, accum);
  finish_k<<<1, 1, 0, stream>>>(accum, out);
}

// Round 17
// 1583.368 us; speedup vs baseline: 1.0629x; 1.0629x over previous
//
#include <hip/hip_runtime.h>
#include <hip/hip_bf16.h>

// CharRNN: 2-layer LSTM LM + softmax CE on MI355X (gfx950).
// Round 17: r15 (best, 1524us) with ONE contained change: the per-step bulk
// load of {h1[t-1], h2[t-2]} issues all 32 dwordx4 loads first and waits
// ONCE (was 4 load8 calls each with an internal vmcnt(0) => 4 serialized
// MALL round trips per step). Everything else identical to r15.
// dims: V=8000, B=64, T=128, H=512.

#define V_SIZE 8000
#define VPAD   8192
#define B_SIZE 64
#define T_SIZE 128
#define H_SIZE 512
#define NG     (4 * H_SIZE)          // 2048 gate columns
#define HB     (H_SIZE * B_SIZE)     // one h time-slice (bf16 elems)
#define RBLK   64                    // recurrence grid (merged blocks)
#define RTH    256                   // recurrence block size
#define SENT   0x7FFF7FFFu

typedef __attribute__((ext_vector_type(8))) short bf16x8;
typedef __attribute__((ext_vector_type(8))) unsigned short u16x8;
typedef __attribute__((ext_vector_type(4))) float f32x4;

// ---------- bf16 helpers (raw ushort storage) ----------
__device__ __forceinline__ float bf2f(unsigned short u) {
  union { unsigned int i; float f; } x; x.i = ((unsigned int)u) << 16; return x.f;
}
__device__ __forceinline__ unsigned short f2bf(float f) {
  union { float f; unsigned int i; } x; x.f = f;
  unsigned int r = x.i + 0x7fffu + ((x.i >> 16) & 1u);
  return (unsigned short)(r >> 16);
}
__device__ __forceinline__ float sigf(float v) { return 1.f / (1.f + __expf(-v)); }
__device__ __forceinline__ float tanhf_fast(float v) {
  return 1.f - 2.f / (__expf(2.f * v) + 1.f);
}

// agent-scope (MALL-coherent) 16B load as 2x u64 atomics (straggler re-poll)
__device__ __forceinline__ bf16x8 aload16(const unsigned short* p) {
  unsigned long long lo = __hip_atomic_load((const unsigned long long*)p,
                                            __ATOMIC_RELAXED, __HIP_MEMORY_SCOPE_AGENT);
  unsigned long long hi = __hip_atomic_load((const unsigned long long*)(p + 4),
                                            __ATOMIC_RELAXED, __HIP_MEMORY_SCOPE_AGENT);
  union { unsigned long long v[2]; bf16x8 b; } u;
  u.v[0] = lo; u.v[1] = hi;
  return u.b;
}
__device__ __forceinline__ unsigned has_sent(bf16x8 v) {
  union { bf16x8 b; unsigned u[4]; } x; x.b = v;
  return (unsigned)((x.u[0] == SENT) | (x.u[1] == SENT) |
                    (x.u[2] == SENT) | (x.u[3] == SENT));
}

// cache-bypassing (sc0 sc1 -> MALL) 16x16B ISSUE-ONLY batch load (no waitcnt).
// Covers byte offsets 0..960 (one full operand: 16 chunks of 32 bf16).
__device__ __forceinline__ void load16_issue(bf16x8* d, const unsigned short* base) {
  asm volatile(
      "global_load_dwordx4 %0, %16, off sc0 sc1\n\t"
      "global_load_dwordx4 %1, %16, off offset:64 sc0 sc1\n\t"
      "global_load_dwordx4 %2, %16, off offset:128 sc0 sc1\n\t"
      "global_load_dwordx4 %3, %16, off offset:192 sc0 sc1\n\t"
      "global_load_dwordx4 %4, %16, off offset:256 sc0 sc1\n\t"
      "global_load_dwordx4 %5, %16, off offset:320 sc0 sc1\n\t"
      "global_load_dwordx4 %6, %16, off offset:384 sc0 sc1\n\t"
      "global_load_dwordx4 %7, %16, off offset:448 sc0 sc1\n\t"
      "global_load_dwordx4 %8, %16, off offset:512 sc0 sc1\n\t"
      "global_load_dwordx4 %9, %16, off offset:576 sc0 sc1\n\t"
      "global_load_dwordx4 %10, %16, off offset:640 sc0 sc1\n\t"
      "global_load_dwordx4 %11, %16, off offset:704 sc0 sc1\n\t"
      "global_load_dwordx4 %12, %16, off offset:768 sc0 sc1\n\t"
      "global_load_dwordx4 %13, %16, off offset:832 sc0 sc1\n\t"
      "global_load_dwordx4 %14, %16, off offset:896 sc0 sc1\n\t"
      "global_load_dwordx4 %15, %16, off offset:960 sc0 sc1"
      : "=v"(d[0]), "=v"(d[1]), "=v"(d[2]), "=v"(d[3]),
        "=v"(d[4]), "=v"(d[5]), "=v"(d[6]), "=v"(d[7]),
        "=v"(d[8]), "=v"(d[9]), "=v"(d[10]), "=v"(d[11]),
        "=v"(d[12]), "=v"(d[13]), "=v"(d[14]), "=v"(d[15])
      : "v"(base)
      : "memory");
}
__device__ __forceinline__ void wait_all_vmem() {
  asm volatile("s_waitcnt vmcnt(0)" ::: "memory");
  __builtin_amdgcn_sched_barrier(0);
}

// ---------------- fill ----------------
__global__ void fill_k(unsigned* __restrict__ p, unsigned v, int n) {
  int i = blockIdx.x * 256 + threadIdx.x;
  if (i < n) p[i] = v;
}

// ---------------- padded bias: bvp[i] = i<V ? bv[i] : -1e30 ----------------
__global__ void bvp_k(const float* __restrict__ bv, float* __restrict__ bvp) {
  int i = blockIdx.x * 256 + threadIdx.x;   // 8192
  bvp[i] = (i < V_SIZE) ? bv[i] : -1e30f;
}

// ---------------- embedding gather -> bf16 x [8192 rows=t*64+b][512] ----------------
__global__ __launch_bounds__(256) void xgather_k(const int* __restrict__ ids,
                                                 const float* __restrict__ emb,
                                                 unsigned short* __restrict__ xb) {
  int g = blockIdx.x * 256 + threadIdx.x;   // 8192 rows x 64 chunks of 8
  int r = g >> 6, c = g & 63;
  int t = r >> 6, b = r & 63;
  int id = ids[(size_t)b * T_SIZE + t];
  const float4* s4 = reinterpret_cast<const float4*>(emb + (size_t)id * H_SIZE + c * 8);
  float4 v0 = s4[0], v1 = s4[1];
  u16x8 o;
  o[0] = f2bf(v0.x); o[1] = f2bf(v0.y); o[2] = f2bf(v0.z); o[3] = f2bf(v0.w);
  o[4] = f2bf(v1.x); o[5] = f2bf(v1.y); o[6] = f2bf(v1.z); o[7] = f2bf(v1.w);
  *reinterpret_cast<u16x8*>(xb + (size_t)r * H_SIZE + c * 8) = o;
}

// ---------------- f32 [K][N] -> bf16 [Npad][K] transpose (64x64 tiles) ----------------
// cols >= Nsrc are written as 0.
__global__ __launch_bounds__(256) void trans_k(const float* __restrict__ src,
                                               unsigned short* __restrict__ dst,
                                               int src_ld, int n_tiles, int Nsrc) {
  __shared__ float tile[64][65];
  const int tid = threadIdx.x;
  const int kt = blockIdx.x / n_tiles, nt = blockIdx.x % n_tiles;
#pragma unroll
  for (int q = 0; q < 16; ++q) {
    int f = tid + 256 * q;
    int r = f >> 6, c = f & 63;
    int col = nt * 64 + c;
    tile[r][c] = (col < Nsrc) ? src[(size_t)(kt * 64 + r) * src_ld + col] : 0.f;
  }
  __syncthreads();
#pragma unroll
  for (int q = 0; q < 2; ++q) {
    int u = tid + 256 * q;
    int n = u >> 3, kg = u & 7;
    u16x8 o;
#pragma unroll
    for (int e = 0; e < 8; ++e) o[e] = f2bf(tile[kg * 8 + e][n]);
    *reinterpret_cast<u16x8*>(dst + (size_t)(nt * 64 + n) * 512 + kt * 64 + kg * 8) = o;
  }
}

// load 8 B-fragments (one K-half) for column vc from a [N][512] bf16 matrix
__device__ __forceinline__ void loadB8(bf16x8* p, const unsigned short* Wb,
                                       int vc, int kh, int kof) {
#pragma unroll
  for (int ks = 0; ks < 8; ++ks)
    p[ks] = *reinterpret_cast<const bf16x8*>(
        Wb + (size_t)vc * 512 + (kh * 8 + ks) * 32 + kof);
}

// ---------------- sentinel dataflow MFMA 2-layer LSTM + input projection ----------------
// (r15 body; only the bulk-load wait structure changed: 32 issues, ONE wait)
__global__ __launch_bounds__(RTH, 1) void recur_k(
    const float* __restrict__ W1, const float* __restrict__ W2,
    const float* __restrict__ b1, const float* __restrict__ b2,
    const unsigned short* __restrict__ xb,
    const unsigned short* __restrict__ hzero,
    unsigned short* __restrict__ h1all, unsigned short* __restrict__ h2all)
{
  __shared__ short wldsX[2 * 16 * 64 * 8];  // 32 KB  W1 x-slice (rows 0..511)
  __shared__ short wlds1[2 * 16 * 64 * 8];  // 32 KB  W1 recurrent slice (rows 512..1023)
  __shared__ short wlds2[2 * 32 * 64 * 8];  // 64 KB  W2 slice
  __shared__ float gbA[64][32];             // 8 KB   L1 gates
  __shared__ float gbB[64][32];             // 8 KB   L2 gates

  const int tid = threadIdx.x;
  const int bid = blockIdx.x;
  const int h0  = bid * 8;
  const int w   = tid >> 6, l = tid & 63;

  {
    for (int idx = tid; idx < 2 * 16 * 64; idx += RTH) {
      int ln2 = idx & 63;
      int ks  = (idx >> 6) % 16;
      int ng  = (idx >> 6) / 16;
      int n   = ln2 & 15;
      int col = (n & 3) * H_SIZE + h0 + ng * 4 + (n >> 2);
      int kb  = ks * 32 + (ln2 >> 4) * 8;
      short* dX = &wldsX[((size_t)(ng * 16 + ks) * 64 + ln2) * 8];
      short* d1 = &wlds1[((size_t)(ng * 16 + ks) * 64 + ln2) * 8];
#pragma unroll
      for (int e = 0; e < 8; ++e) {
        dX[e] = (short)f2bf(W1[(size_t)(kb + e) * NG + col]);
        d1[e] = (short)f2bf(W1[(size_t)(H_SIZE + kb + e) * NG + col]);
      }
    }
    for (int idx = tid; idx < 2 * 32 * 64; idx += RTH) {
      int ln2 = idx & 63;
      int ks  = (idx >> 6) % 32;
      int ng  = (idx >> 6) / 32;
      int n   = ln2 & 15;
      int col = (n & 3) * H_SIZE + h0 + ng * 4 + (n >> 2);
      int kb  = ks * 32 + (ln2 >> 4) * 8;
      short* dst = &wlds2[((size_t)(ng * 32 + ks) * 64 + ln2) * 8];
#pragma unroll
      for (int e = 0; e < 8; ++e)
        dst[e] = (short)f2bf(W2[(size_t)(kb + e) * NG + col]);
    }
  }

  const int pb = tid >> 2, pq = tid & 3;
  float c1[2] = {0.f, 0.f}, c2[2] = {0.f, 0.f};
  float bias1[2][4], bias2[2][4];
#pragma unroll
  for (int hh = 0; hh < 2; ++hh)
#pragma unroll
    for (int g = 0; g < 4; ++g) {
      bias1[hh][g] = b1[g * H_SIZE + h0 + 2 * pq + hh];
      bias2[hh][g] = b2[g * H_SIZE + h0 + 2 * pq + hh];
    }
  __syncthreads();

  const int arow = w * 16 + (l & 15);
  const int kof  = (l >> 4) * 8;

  for (int t = 0; t <= T_SIZE; ++t) {
    f32x4 acc0 = {0.f, 0.f, 0.f, 0.f};
    f32x4 acc1 = {0.f, 0.f, 0.f, 0.f};
    if (t < T_SIZE) {
      const unsigned short* xr = xb + ((size_t)t * 64 + arow) * H_SIZE + kof;
#pragma unroll
      for (int ks = 0; ks < 16; ++ks) {
        bf16x8 avx = *reinterpret_cast<const bf16x8*>(xr + ks * 32);
        bf16x8 bv0 = *reinterpret_cast<const bf16x8*>(&wldsX[((size_t)(0 * 16 + ks) * 64 + l) * 8]);
        bf16x8 bv1 = *reinterpret_cast<const bf16x8*>(&wldsX[((size_t)(1 * 16 + ks) * 64 + l) * 8]);
        acc0 = __builtin_amdgcn_mfma_f32_16x16x32_bf16(avx, bv0, acc0, 0, 0, 0);
        acc1 = __builtin_amdgcn_mfma_f32_16x16x32_bf16(avx, bv1, acc1, 0, 0, 0);
      }
    }

    // ---- bulk load: issue ALL 32 dwordx4, then ONE vmcnt(0) ----
    const unsigned short* h1src = ((t == 0) ? hzero : h1all + (size_t)(t - 1) * HB)
                                  + (size_t)arow * H_SIZE + kof;
    const unsigned short* h2src = ((t < 2) ? hzero : h2all + (size_t)(t - 2) * HB)
                                  + (size_t)arow * H_SIZE + kof;
    bf16x8 av1[16], av2[16];
    load16_issue(av1, h1src);
    load16_issue(av2, h2src);
    wait_all_vmem();
    {
      unsigned p1m = 0, p2m = 0;
#pragma unroll
      for (int ks = 0; ks < 16; ++ks) {
        p1m |= has_sent(av1[ks]) << ks;
        p2m |= has_sent(av2[ks]) << ks;
      }
      while (p1m | p2m) {
        __builtin_amdgcn_s_sleep(2);
#pragma unroll
        for (int ks = 0; ks < 16; ++ks)
          if ((p1m >> ks) & 1) {
            av1[ks] = aload16(h1src + ks * 32);
            if (!has_sent(av1[ks])) p1m &= ~(1u << ks);
          }
#pragma unroll
        for (int ks = 0; ks < 16; ++ks)
          if ((p2m >> ks) & 1) {
            av2[ks] = aload16(h2src + ks * 32);
            if (!has_sent(av2[ks])) p2m &= ~(1u << ks);
          }
      }
    }

    if (t < T_SIZE) {
#pragma unroll
      for (int ks = 0; ks < 16; ++ks) {
        bf16x8 bv0 = *reinterpret_cast<const bf16x8*>(&wlds1[((size_t)(0 * 16 + ks) * 64 + l) * 8]);
        bf16x8 bv1 = *reinterpret_cast<const bf16x8*>(&wlds1[((size_t)(1 * 16 + ks) * 64 + l) * 8]);
        acc0 = __builtin_amdgcn_mfma_f32_16x16x32_bf16(av1[ks], bv0, acc0, 0, 0, 0);
        acc1 = __builtin_amdgcn_mfma_f32_16x16x32_bf16(av1[ks], bv1, acc1, 0, 0, 0);
      }
      {
        const int crow = w * 16 + ((l >> 4) << 2);
        const int ccol = l & 15;
#pragma unroll
        for (int r = 0; r < 4; ++r) {
          gbA[crow + r][ccol]      = acc0[r];
          gbA[crow + r][16 + ccol] = acc1[r];
        }
      }
      __syncthreads();
      unsigned short hbv[2];
#pragma unroll
      for (int hh = 0; hh < 2; ++hh) {
        const int hl = 2 * pq + hh;
        const int ng = hl >> 2, jj = hl & 3;
        float g[4];
#pragma unroll
        for (int gg = 0; gg < 4; ++gg)
          g[gg] = gbA[pb][ng * 16 + jj * 4 + gg] + bias1[hh][gg];
        float cn = c1[hh] * sigf(g[2]) + sigf(g[0]) * tanhf_fast(g[1]);
        float hn = tanhf_fast(cn) * sigf(g[3]);
        c1[hh] = cn;
        hbv[hh] = f2bf(hn);
      }
      unsigned pack = (unsigned)hbv[0] | ((unsigned)hbv[1] << 16);
      __hip_atomic_store((unsigned*)(h1all + (size_t)t * HB + (size_t)pb * H_SIZE
                                     + h0 + 2 * pq),
                         pack, __ATOMIC_RELAXED, __HIP_MEMORY_SCOPE_AGENT);
    }

    if (t >= 1) {
      f32x4 bcc0 = {0.f, 0.f, 0.f, 0.f};
      f32x4 bcc1 = {0.f, 0.f, 0.f, 0.f};
#pragma unroll
      for (int ks = 0; ks < 16; ++ks) {   // h2[t-2] rows 512..1023
        bf16x8 bv0 = *reinterpret_cast<const bf16x8*>(&wlds2[((size_t)(0 * 32 + 16 + ks) * 64 + l) * 8]);
        bf16x8 bv1 = *reinterpret_cast<const bf16x8*>(&wlds2[((size_t)(1 * 32 + 16 + ks) * 64 + l) * 8]);
        bcc0 = __builtin_amdgcn_mfma_f32_16x16x32_bf16(av2[ks], bv0, bcc0, 0, 0, 0);
        bcc1 = __builtin_amdgcn_mfma_f32_16x16x32_bf16(av2[ks], bv1, bcc1, 0, 0, 0);
      }
#pragma unroll
      for (int ks = 0; ks < 16; ++ks) {   // h1[t-1] rows 0..511
        bf16x8 bv0 = *reinterpret_cast<const bf16x8*>(&wlds2[((size_t)(0 * 32 + ks) * 64 + l) * 8]);
        bf16x8 bv1 = *reinterpret_cast<const bf16x8*>(&wlds2[((size_t)(1 * 32 + ks) * 64 + l) * 8]);
        bcc0 = __builtin_amdgcn_mfma_f32_16x16x32_bf16(av1[ks], bv0, bcc0, 0, 0, 0);
        bcc1 = __builtin_amdgcn_mfma_f32_16x16x32_bf16(av1[ks], bv1, bcc1, 0, 0, 0);
      }
      {
        const int crow = w * 16 + ((l >> 4) << 2);
        const int ccol = l & 15;
#pragma unroll
        for (int r = 0; r < 4; ++r) {
          gbB[crow + r][ccol]      = bcc0[r];
          gbB[crow + r][16 + ccol] = bcc1[r];
        }
      }
      __syncthreads();
      unsigned short hbv[2];
#pragma unroll
      for (int hh = 0; hh < 2; ++hh) {
        const int hl = 2 * pq + hh;
        const int ng = hl >> 2, jj = hl & 3;
        float g[4];
#pragma unroll
        for (int gg = 0; gg < 4; ++gg)
          g[gg] = gbB[pb][ng * 16 + jj * 4 + gg] + bias2[hh][gg];
        float cn = c2[hh] * sigf(g[2]) + sigf(g[0]) * tanhf_fast(g[1]);
        float hn = tanhf_fast(cn) * sigf(g[3]);
        c2[hh] = cn;
        hbv[hh] = f2bf(hn);
      }
      unsigned pack = (unsigned)hbv[0] | ((unsigned)hbv[1] << 16);
      __hip_atomic_store((unsigned*)(h2all + (size_t)(t - 1) * HB
                                     + (size_t)pb * H_SIZE + h0 + 2 * pq),
                         pack, __ATOMIC_RELAXED, __HIP_MEMORY_SCOPE_AGENT);
    }

    __syncthreads();   // protect gbA/gbB for next iteration (also drains stores)
  }
}

// ---------------- CE v2: 256 rows x 1024 cols per block, no-max lse ----------------
// grid 256 = 32 row-blocks x 8 col-strips; 512 threads (8 waves share cols).
__global__ __launch_bounds__(512) void ce2_k(const unsigned short* __restrict__ outs,
                                             const unsigned short* __restrict__ Wvb,
                                             const float* __restrict__ bvp,
                                             const int* __restrict__ tgts,
                                             float* __restrict__ psm,
                                             float* __restrict__ ptg) {
  const int tid = threadIdx.x;
  const int rb = blockIdx.x >> 3, cb = blockIdx.x & 7;
  const int w = tid >> 6, l = tid & 63;
  const int kof = (l >> 4) * 8;
  const int ln = l & 15;
  const int r0 = rb * 256 + w * 32;
  const int cbase = cb * 1024;

  bf16x8 av0[16], av1[16];
#pragma unroll
  for (int ks = 0; ks < 16; ++ks) {
    av0[ks] = *reinterpret_cast<const bf16x8*>(
        outs + (size_t)(r0 + ln) * H_SIZE + ks * 32 + kof);
    av1[ks] = *reinterpret_cast<const bf16x8*>(
        outs + (size_t)(r0 + 16 + ln) * H_SIZE + ks * 32 + kof);
  }
  int lbl0[4], lbl1[4];
#pragma unroll
  for (int r = 0; r < 4; ++r) {
    int rr = r0 + ((l >> 4) << 2) + r;
    lbl0[r] = tgts[(size_t)(rr & 63) * T_SIZE + (rr >> 6)];
    rr += 16;
    lbl1[r] = tgts[(size_t)(rr & 63) * T_SIZE + (rr >> 6)];
  }

  float sm0[4] = {0.f, 0.f, 0.f, 0.f}, sm1[4] = {0.f, 0.f, 0.f, 0.f};
  float tg0[4] = {0.f, 0.f, 0.f, 0.f}, tg1[4] = {0.f, 0.f, 0.f, 0.f};

  bf16x8 p0[8], p1[8];
  loadB8(p0, Wvb, cbase + ln, 0, kof);
  for (int ct = 0; ct < 64; ++ct) {
    const int vc = cbase + ct * 16 + ln;
    const int vcn = cbase + ((ct < 63) ? ct + 1 : ct) * 16 + ln;
    f32x4 a0 = {0.f, 0.f, 0.f, 0.f};
    f32x4 a1 = {0.f, 0.f, 0.f, 0.f};
    loadB8(p1, Wvb, vc, 1, kof);
#pragma unroll
    for (int ks = 0; ks < 8; ++ks) {
      a0 = __builtin_amdgcn_mfma_f32_16x16x32_bf16(av0[ks], p0[ks], a0, 0, 0, 0);
      a1 = __builtin_amdgcn_mfma_f32_16x16x32_bf16(av1[ks], p0[ks], a1, 0, 0, 0);
    }
    loadB8(p0, Wvb, vcn, 0, kof);
#pragma unroll
    for (int ks = 0; ks < 8; ++ks) {
      a0 = __builtin_amdgcn_mfma_f32_16x16x32_bf16(av0[8 + ks], p1[ks], a0, 0, 0, 0);
      a1 = __builtin_amdgcn_mfma_f32_16x16x32_bf16(av1[8 + ks], p1[ks], a1, 0, 0, 0);
    }
    float bb = bvp[vc];
#pragma unroll
    for (int r = 0; r < 4; ++r) {
      float lg = a0[r] + bb;
      sm0[r] += __expf(lg);
      tg0[r] += (vc == lbl0[r]) ? lg : 0.f;
      float lh = a1[r] + bb;
      sm1[r] += __expf(lh);
      tg1[r] += (vc == lbl1[r]) ? lh : 0.f;
    }
  }

#pragma unroll
  for (int off = 1; off <= 8; off <<= 1) {
#pragma unroll
    for (int r = 0; r < 4; ++r) {
      sm0[r] += __shfl_xor(sm0[r], off, 64);
      tg0[r] += __shfl_xor(tg0[r], off, 64);
      sm1[r] += __shfl_xor(sm1[r], off, 64);
      tg1[r] += __shfl_xor(tg1[r], off, 64);
    }
  }
  if (ln == 0) {
    int rrw = r0 + ((l >> 4) << 2);
#pragma unroll
    for (int r = 0; r < 4; ++r) {
      psm[(size_t)cb * 8192 + rrw + r]      = sm0[r];
      ptg[(size_t)cb * 8192 + rrw + r]      = tg0[r];
      psm[(size_t)cb * 8192 + rrw + 16 + r] = sm1[r];
      ptg[(size_t)cb * 8192 + rrw + 16 + r] = tg1[r];
    }
  }
}

// ---------------- merge 8 col-strip partials, per-row loss, sum ----------------
__global__ __launch_bounds__(256) void cemerge_k(const float* __restrict__ psm,
                                                 const float* __restrict__ ptg,
                                                 float* __restrict__ accum) {
  int g = blockIdx.x * 256 + threadIdx.x;   // 0..8191
  float S = 0.f, T = 0.f;
#pragma unroll
  for (int j = 0; j < 8; ++j) {
    S += psm[(size_t)j * 8192 + g];
    T += ptg[(size_t)j * 8192 + g];
  }
  float loss = logf(S) - T;
#pragma unroll
  for (int off = 32; off >= 1; off >>= 1)
    loss += __shfl_xor(loss, off, 64);
  if ((threadIdx.x & 63) == 0) atomicAdd(accum, loss);
}

__global__ void finish_k(const float* __restrict__ accum, float* __restrict__ out) {
  out[0] = accum[0] * (1.f / (float)(B_SIZE * T_SIZE));
}

// ---------------- launcher ----------------
extern "C" void kernel_launch(void* const* d_in, const int* in_sizes, int n_in,
                              void* d_out, int out_size, void* d_ws, size_t ws_size,
                              hipStream_t stream) {
  const int*   ids  = (const int*)  d_in[0];
  const int*   tgts = (const int*)  d_in[1];
  const float* emb  = (const float*)d_in[2];
  const float* W1   = (const float*)d_in[3];
  const float* b1   = (const float*)d_in[4];
  const float* W2   = (const float*)d_in[5];
  const float* b2   = (const float*)d_in[6];
  const float* Wv   = (const float*)d_in[7];
  const float* bv   = (const float*)d_in[8];
  float* out = (float*)d_out;

  // ws layout (bytes), total ~34.2 MB:
  char* ws = (char*)d_ws;
  unsigned short* xb    = (unsigned short*)(ws);                 //  8,388,608
  unsigned short* outsb = (unsigned short*)(ws + 8388608);       //  8,388,608 (=h2all)
  unsigned short* h1all = (unsigned short*)(ws + 16777216);      //  8,388,608
  unsigned short* Wvb   = (unsigned short*)(ws + 25165824);      //  8,388,608 (padded 8192x512)
  unsigned short* hzero = (unsigned short*)(ws + 33554432);      //     65,536
  float*          bvp   = (float*)         (ws + 33619968);      //     32,768
  float*          accum = (float*)         (ws + 33652736);      //          4 (pad 64)
  float*          psm   = (float*)         (ws + 33652800);      //    262,144
  float*          ptg   = (float*)         (ws + 33914944);      //    262,144

  // zero hzero + bvp + accum (contiguous 98,368 B = 24,592 u32)
  fill_k<<<97, 256, 0, stream>>>((unsigned*)hzero, 0u, 24592);
  // sentinel-fill outsb + h1all (contiguous 16,777,216 B = 4,194,304 u32)
  fill_k<<<16384, 256, 0, stream>>>((unsigned*)outsb, SENT, 4194304);

  bvp_k<<<32, 256, 0, stream>>>(bv, bvp);
  xgather_k<<<2048, 256, 0, stream>>>(ids, emb, xb);
  trans_k<<<1024, 256, 0, stream>>>(Wv, Wvb, V_SIZE, 128, V_SIZE); // padded transpose

  {
    void* args[] = { (void*)&W1, (void*)&W2, (void*)&b1, (void*)&b2,
                     (void*)&xb, (void*)&hzero, (void*)&h1all, (void*)&outsb };
    hipError_t e = hipLaunchCooperativeKernel((const void*)recur_k,
                                              dim3(RBLK), dim3(RTH),
                                              args, 0, stream);
    if (e != hipSuccess) {
      recur_k<<<dim3(RBLK), dim3(RTH), 0, stream>>>(W1, W2, b1, b2, xb, hzero,
                                                    h1all, outsb);
    }
  }

  ce2_k<<<256, 512, 0, stream>>>(outsb, Wvb, bvp, tgts, psm, ptg);
  cemerge_k<<<32, 256, 0, stream>>>(psm, ptg, accum);
  finish_k<<<1, 1, 0, stream>>>(accum, out);
}

// Round 18
// 1521.314 us; speedup vs baseline: 1.1062x; 1.0408x over previous
//
#include <hip/hip_runtime.h>
#include <hip/hip_bf16.h>

// CharRNN: 2-layer LSTM LM + softmax CE on MI355X (gfx950).
// Round 18: revert to r15 (best, 1524us): r14 recurrence (folded input
// projection, 64 merged blocks, 4x load8_mall bulk loads + masked per-chunk
// re-poll) + CE v2 (256r x 1024c blocks, no-max lse). One micro-change vs
// r15: tight re-poll spin (s_sleep removed) to cut detect-latency quanta.
// dims: V=8000, B=64, T=128, H=512.

#define V_SIZE 8000
#define VPAD   8192
#define B_SIZE 64
#define T_SIZE 128
#define H_SIZE 512
#define NG     (4 * H_SIZE)          // 2048 gate columns
#define HB     (H_SIZE * B_SIZE)     // one h time-slice (bf16 elems)
#define RBLK   64                    // recurrence grid (merged blocks)
#define RTH    256                   // recurrence block size
#define SENT   0x7FFF7FFFu

typedef __attribute__((ext_vector_type(8))) short bf16x8;
typedef __attribute__((ext_vector_type(8))) unsigned short u16x8;
typedef __attribute__((ext_vector_type(4))) float f32x4;

// ---------- bf16 helpers (raw ushort storage) ----------
__device__ __forceinline__ float bf2f(unsigned short u) {
  union { unsigned int i; float f; } x; x.i = ((unsigned int)u) << 16; return x.f;
}
__device__ __forceinline__ unsigned short f2bf(float f) {
  union { float f; unsigned int i; } x; x.f = f;
  unsigned int r = x.i + 0x7fffu + ((x.i >> 16) & 1u);
  return (unsigned short)(r >> 16);
}
__device__ __forceinline__ float sigf(float v) { return 1.f / (1.f + __expf(-v)); }
__device__ __forceinline__ float tanhf_fast(float v) {
  return 1.f - 2.f / (__expf(2.f * v) + 1.f);
}

// agent-scope (MALL-coherent) 16B load as 2x u64 atomics (straggler re-poll)
__device__ __forceinline__ bf16x8 aload16(const unsigned short* p) {
  unsigned long long lo = __hip_atomic_load((const unsigned long long*)p,
                                            __ATOMIC_RELAXED, __HIP_MEMORY_SCOPE_AGENT);
  unsigned long long hi = __hip_atomic_load((const unsigned long long*)(p + 4),
                                            __ATOMIC_RELAXED, __HIP_MEMORY_SCOPE_AGENT);
  union { unsigned long long v[2]; bf16x8 b; } u;
  u.v[0] = lo; u.v[1] = hi;
  return u.b;
}
__device__ __forceinline__ unsigned has_sent(bf16x8 v) {
  union { bf16x8 b; unsigned u[4]; } x; x.b = v;
  return (unsigned)((x.u[0] == SENT) | (x.u[1] == SENT) |
                    (x.u[2] == SENT) | (x.u[3] == SENT));
}

// cache-bypassing (sc0 sc1 -> MALL) 8x16B batch load, one waitcnt.
__device__ __forceinline__ void load8_mall(bf16x8* d, const unsigned short* base) {
  asm volatile(
      "global_load_dwordx4 %0, %8, off sc0 sc1\n\t"
      "global_load_dwordx4 %1, %8, off offset:64 sc0 sc1\n\t"
      "global_load_dwordx4 %2, %8, off offset:128 sc0 sc1\n\t"
      "global_load_dwordx4 %3, %8, off offset:192 sc0 sc1\n\t"
      "global_load_dwordx4 %4, %8, off offset:256 sc0 sc1\n\t"
      "global_load_dwordx4 %5, %8, off offset:320 sc0 sc1\n\t"
      "global_load_dwordx4 %6, %8, off offset:384 sc0 sc1\n\t"
      "global_load_dwordx4 %7, %8, off offset:448 sc0 sc1\n\t"
      "s_waitcnt vmcnt(0)"
      : "=v"(d[0]), "=v"(d[1]), "=v"(d[2]), "=v"(d[3]),
        "=v"(d[4]), "=v"(d[5]), "=v"(d[6]), "=v"(d[7])
      : "v"(base)
      : "memory");
}

// ---------------- fill ----------------
__global__ void fill_k(unsigned* __restrict__ p, unsigned v, int n) {
  int i = blockIdx.x * 256 + threadIdx.x;
  if (i < n) p[i] = v;
}

// ---------------- padded bias: bvp[i] = i<V ? bv[i] : -1e30 ----------------
__global__ void bvp_k(const float* __restrict__ bv, float* __restrict__ bvp) {
  int i = blockIdx.x * 256 + threadIdx.x;   // 8192
  bvp[i] = (i < V_SIZE) ? bv[i] : -1e30f;
}

// ---------------- embedding gather -> bf16 x [8192 rows=t*64+b][512] ----------------
__global__ __launch_bounds__(256) void xgather_k(const int* __restrict__ ids,
                                                 const float* __restrict__ emb,
                                                 unsigned short* __restrict__ xb) {
  int g = blockIdx.x * 256 + threadIdx.x;   // 8192 rows x 64 chunks of 8
  int r = g >> 6, c = g & 63;
  int t = r >> 6, b = r & 63;
  int id = ids[(size_t)b * T_SIZE + t];
  const float4* s4 = reinterpret_cast<const float4*>(emb + (size_t)id * H_SIZE + c * 8);
  float4 v0 = s4[0], v1 = s4[1];
  u16x8 o;
  o[0] = f2bf(v0.x); o[1] = f2bf(v0.y); o[2] = f2bf(v0.z); o[3] = f2bf(v0.w);
  o[4] = f2bf(v1.x); o[5] = f2bf(v1.y); o[6] = f2bf(v1.z); o[7] = f2bf(v1.w);
  *reinterpret_cast<u16x8*>(xb + (size_t)r * H_SIZE + c * 8) = o;
}

// ---------------- f32 [K][N] -> bf16 [Npad][K] transpose (64x64 tiles) ----------------
// cols >= Nsrc are written as 0.
__global__ __launch_bounds__(256) void trans_k(const float* __restrict__ src,
                                               unsigned short* __restrict__ dst,
                                               int src_ld, int n_tiles, int Nsrc) {
  __shared__ float tile[64][65];
  const int tid = threadIdx.x;
  const int kt = blockIdx.x / n_tiles, nt = blockIdx.x % n_tiles;
#pragma unroll
  for (int q = 0; q < 16; ++q) {
    int f = tid + 256 * q;
    int r = f >> 6, c = f & 63;
    int col = nt * 64 + c;
    tile[r][c] = (col < Nsrc) ? src[(size_t)(kt * 64 + r) * src_ld + col] : 0.f;
  }
  __syncthreads();
#pragma unroll
  for (int q = 0; q < 2; ++q) {
    int u = tid + 256 * q;
    int n = u >> 3, kg = u & 7;
    u16x8 o;
#pragma unroll
    for (int e = 0; e < 8; ++e) o[e] = f2bf(tile[kg * 8 + e][n]);
    *reinterpret_cast<u16x8*>(dst + (size_t)(nt * 64 + n) * 512 + kt * 64 + kg * 8) = o;
  }
}

// load 8 B-fragments (one K-half) for column vc from a [N][512] bf16 matrix
__device__ __forceinline__ void loadB8(bf16x8* p, const unsigned short* Wb,
                                       int vc, int kh, int kof) {
#pragma unroll
  for (int ks = 0; ks < 8; ++ks)
    p[ks] = *reinterpret_cast<const bf16x8*>(
        Wb + (size_t)vc * 512 + (kh * 8 + ks) * 32 + kof);
}

// ---------------- sentinel dataflow MFMA 2-layer LSTM + input projection ----------------
// (r14/r15 body) 64 blocks; block owns 8 h-cols of BOTH layers.
__global__ __launch_bounds__(RTH, 1) void recur_k(
    const float* __restrict__ W1, const float* __restrict__ W2,
    const float* __restrict__ b1, const float* __restrict__ b2,
    const unsigned short* __restrict__ xb,
    const unsigned short* __restrict__ hzero,
    unsigned short* __restrict__ h1all, unsigned short* __restrict__ h2all)
{
  __shared__ short wldsX[2 * 16 * 64 * 8];  // 32 KB  W1 x-slice (rows 0..511)
  __shared__ short wlds1[2 * 16 * 64 * 8];  // 32 KB  W1 recurrent slice (rows 512..1023)
  __shared__ short wlds2[2 * 32 * 64 * 8];  // 64 KB  W2 slice
  __shared__ float gbA[64][32];             // 8 KB   L1 gates
  __shared__ float gbB[64][32];             // 8 KB   L2 gates

  const int tid = threadIdx.x;
  const int bid = blockIdx.x;
  const int h0  = bid * 8;
  const int w   = tid >> 6, l = tid & 63;

  {
    for (int idx = tid; idx < 2 * 16 * 64; idx += RTH) {
      int ln2 = idx & 63;
      int ks  = (idx >> 6) % 16;
      int ng  = (idx >> 6) / 16;
      int n   = ln2 & 15;
      int col = (n & 3) * H_SIZE + h0 + ng * 4 + (n >> 2);
      int kb  = ks * 32 + (ln2 >> 4) * 8;
      short* dX = &wldsX[((size_t)(ng * 16 + ks) * 64 + ln2) * 8];
      short* d1 = &wlds1[((size_t)(ng * 16 + ks) * 64 + ln2) * 8];
#pragma unroll
      for (int e = 0; e < 8; ++e) {
        dX[e] = (short)f2bf(W1[(size_t)(kb + e) * NG + col]);
        d1[e] = (short)f2bf(W1[(size_t)(H_SIZE + kb + e) * NG + col]);
      }
    }
    for (int idx = tid; idx < 2 * 32 * 64; idx += RTH) {
      int ln2 = idx & 63;
      int ks  = (idx >> 6) % 32;
      int ng  = (idx >> 6) / 32;
      int n   = ln2 & 15;
      int col = (n & 3) * H_SIZE + h0 + ng * 4 + (n >> 2);
      int kb  = ks * 32 + (ln2 >> 4) * 8;
      short* dst = &wlds2[((size_t)(ng * 32 + ks) * 64 + ln2) * 8];
#pragma unroll
      for (int e = 0; e < 8; ++e)
        dst[e] = (short)f2bf(W2[(size_t)(kb + e) * NG + col]);
    }
  }

  const int pb = tid >> 2, pq = tid & 3;
  float c1[2] = {0.f, 0.f}, c2[2] = {0.f, 0.f};
  float bias1[2][4], bias2[2][4];
#pragma unroll
  for (int hh = 0; hh < 2; ++hh)
#pragma unroll
    for (int g = 0; g < 4; ++g) {
      bias1[hh][g] = b1[g * H_SIZE + h0 + 2 * pq + hh];
      bias2[hh][g] = b2[g * H_SIZE + h0 + 2 * pq + hh];
    }
  __syncthreads();

  const int arow = w * 16 + (l & 15);
  const int kof  = (l >> 4) * 8;

  for (int t = 0; t <= T_SIZE; ++t) {
    f32x4 acc0 = {0.f, 0.f, 0.f, 0.f};
    f32x4 acc1 = {0.f, 0.f, 0.f, 0.f};
    if (t < T_SIZE) {
      const unsigned short* xr = xb + ((size_t)t * 64 + arow) * H_SIZE + kof;
#pragma unroll
      for (int ks = 0; ks < 16; ++ks) {
        bf16x8 avx = *reinterpret_cast<const bf16x8*>(xr + ks * 32);
        bf16x8 bv0 = *reinterpret_cast<const bf16x8*>(&wldsX[((size_t)(0 * 16 + ks) * 64 + l) * 8]);
        bf16x8 bv1 = *reinterpret_cast<const bf16x8*>(&wldsX[((size_t)(1 * 16 + ks) * 64 + l) * 8]);
        acc0 = __builtin_amdgcn_mfma_f32_16x16x32_bf16(avx, bv0, acc0, 0, 0, 0);
        acc1 = __builtin_amdgcn_mfma_f32_16x16x32_bf16(avx, bv1, acc1, 0, 0, 0);
      }
    }

    // ---- wide bulk load of h1[t-1], h2[t-2] + masked per-chunk re-poll ----
    const unsigned short* h1src = ((t == 0) ? hzero : h1all + (size_t)(t - 1) * HB)
                                  + (size_t)arow * H_SIZE + kof;
    const unsigned short* h2src = ((t < 2) ? hzero : h2all + (size_t)(t - 2) * HB)
                                  + (size_t)arow * H_SIZE + kof;
    bf16x8 av1[16], av2[16];
    load8_mall(av1, h1src);
    load8_mall(av1 + 8, h1src + 256);
    load8_mall(av2, h2src);
    load8_mall(av2 + 8, h2src + 256);
    {
      unsigned p1m = 0, p2m = 0;
#pragma unroll
      for (int ks = 0; ks < 16; ++ks) {
        p1m |= has_sent(av1[ks]) << ks;
        p2m |= has_sent(av2[ks]) << ks;
      }
      while (p1m | p2m) {
#pragma unroll
        for (int ks = 0; ks < 16; ++ks)
          if ((p1m >> ks) & 1) {
            av1[ks] = aload16(h1src + ks * 32);
            if (!has_sent(av1[ks])) p1m &= ~(1u << ks);
          }
#pragma unroll
        for (int ks = 0; ks < 16; ++ks)
          if ((p2m >> ks) & 1) {
            av2[ks] = aload16(h2src + ks * 32);
            if (!has_sent(av2[ks])) p2m &= ~(1u << ks);
          }
      }
    }

    // ================= L1(t): h-part MFMA + pointwise + store =================
    if (t < T_SIZE) {
#pragma unroll
      for (int ks = 0; ks < 16; ++ks) {
        bf16x8 bv0 = *reinterpret_cast<const bf16x8*>(&wlds1[((size_t)(0 * 16 + ks) * 64 + l) * 8]);
        bf16x8 bv1 = *reinterpret_cast<const bf16x8*>(&wlds1[((size_t)(1 * 16 + ks) * 64 + l) * 8]);
        acc0 = __builtin_amdgcn_mfma_f32_16x16x32_bf16(av1[ks], bv0, acc0, 0, 0, 0);
        acc1 = __builtin_amdgcn_mfma_f32_16x16x32_bf16(av1[ks], bv1, acc1, 0, 0, 0);
      }
      {
        const int crow = w * 16 + ((l >> 4) << 2);
        const int ccol = l & 15;
#pragma unroll
        for (int r = 0; r < 4; ++r) {
          gbA[crow + r][ccol]      = acc0[r];
          gbA[crow + r][16 + ccol] = acc1[r];
        }
      }
      __syncthreads();
      unsigned short hbv[2];
#pragma unroll
      for (int hh = 0; hh < 2; ++hh) {
        const int hl = 2 * pq + hh;
        const int ng = hl >> 2, jj = hl & 3;
        float g[4];
#pragma unroll
        for (int gg = 0; gg < 4; ++gg)
          g[gg] = gbA[pb][ng * 16 + jj * 4 + gg] + bias1[hh][gg];
        float cn = c1[hh] * sigf(g[2]) + sigf(g[0]) * tanhf_fast(g[1]);
        float hn = tanhf_fast(cn) * sigf(g[3]);
        c1[hh] = cn;
        hbv[hh] = f2bf(hn);
      }
      unsigned pack = (unsigned)hbv[0] | ((unsigned)hbv[1] << 16);
      __hip_atomic_store((unsigned*)(h1all + (size_t)t * HB + (size_t)pb * H_SIZE
                                     + h0 + 2 * pq),
                         pack, __ATOMIC_RELAXED, __HIP_MEMORY_SCOPE_AGENT);
    }

    // ================= L2(t-1): MFMA + pointwise + store =================
    if (t >= 1) {
      f32x4 bcc0 = {0.f, 0.f, 0.f, 0.f};
      f32x4 bcc1 = {0.f, 0.f, 0.f, 0.f};
#pragma unroll
      for (int ks = 0; ks < 16; ++ks) {   // h2[t-2] rows 512..1023
        bf16x8 bv0 = *reinterpret_cast<const bf16x8*>(&wlds2[((size_t)(0 * 32 + 16 + ks) * 64 + l) * 8]);
        bf16x8 bv1 = *reinterpret_cast<const bf16x8*>(&wlds2[((size_t)(1 * 32 + 16 + ks) * 64 + l) * 8]);
        bcc0 = __builtin_amdgcn_mfma_f32_16x16x32_bf16(av2[ks], bv0, bcc0, 0, 0, 0);
        bcc1 = __builtin_amdgcn_mfma_f32_16x16x32_bf16(av2[ks], bv1, bcc1, 0, 0, 0);
      }
#pragma unroll
      for (int ks = 0; ks < 16; ++ks) {   // h1[t-1] rows 0..511
        bf16x8 bv0 = *reinterpret_cast<const bf16x8*>(&wlds2[((size_t)(0 * 32 + ks) * 64 + l) * 8]);
        bf16x8 bv1 = *reinterpret_cast<const bf16x8*>(&wlds2[((size_t)(1 * 32 + ks) * 64 + l) * 8]);
        bcc0 = __builtin_amdgcn_mfma_f32_16x16x32_bf16(av1[ks], bv0, bcc0, 0, 0, 0);
        bcc1 = __builtin_amdgcn_mfma_f32_16x16x32_bf16(av1[ks], bv1, bcc1, 0, 0, 0);
      }
      {
        const int crow = w * 16 + ((l >> 4) << 2);
        const int ccol = l & 15;
#pragma unroll
        for (int r = 0; r < 4; ++r) {
          gbB[crow + r][ccol]      = bcc0[r];
          gbB[crow + r][16 + ccol] = bcc1[r];
        }
      }
      __syncthreads();
      unsigned short hbv[2];
#pragma unroll
      for (int hh = 0; hh < 2; ++hh) {
        const int hl = 2 * pq + hh;
        const int ng = hl >> 2, jj = hl & 3;
        float g[4];
#pragma unroll
        for (int gg = 0; gg < 4; ++gg)
          g[gg] = gbB[pb][ng * 16 + jj * 4 + gg] + bias2[hh][gg];
        float cn = c2[hh] * sigf(g[2]) + sigf(g[0]) * tanhf_fast(g[1]);
        float hn = tanhf_fast(cn) * sigf(g[3]);
        c2[hh] = cn;
        hbv[hh] = f2bf(hn);
      }
      unsigned pack = (unsigned)hbv[0] | ((unsigned)hbv[1] << 16);
      __hip_atomic_store((unsigned*)(h2all + (size_t)(t - 1) * HB
                                     + (size_t)pb * H_SIZE + h0 + 2 * pq),
                         pack, __ATOMIC_RELAXED, __HIP_MEMORY_SCOPE_AGENT);
    }

    __syncthreads();   // protect gbA/gbB for next iteration
  }
}

// ---------------- CE v2: 256 rows x 1024 cols per block, no-max lse ----------------
// grid 256 = 32 row-blocks x 8 col-strips; 512 threads (8 waves share cols).
__global__ __launch_bounds__(512) void ce2_k(const unsigned short* __restrict__ outs,
                                             const unsigned short* __restrict__ Wvb,
                                             const float* __restrict__ bvp,
                                             const int* __restrict__ tgts,
                                             float* __restrict__ psm,
                                             float* __restrict__ ptg) {
  const int tid = threadIdx.x;
  const int rb = blockIdx.x >> 3, cb = blockIdx.x & 7;
  const int w = tid >> 6, l = tid & 63;
  const int kof = (l >> 4) * 8;
  const int ln = l & 15;
  const int r0 = rb * 256 + w * 32;
  const int cbase = cb * 1024;

  bf16x8 av0[16], av1[16];
#pragma unroll
  for (int ks = 0; ks < 16; ++ks) {
    av0[ks] = *reinterpret_cast<const bf16x8*>(
        outs + (size_t)(r0 + ln) * H_SIZE + ks * 32 + kof);
    av1[ks] = *reinterpret_cast<const bf16x8*>(
        outs + (size_t)(r0 + 16 + ln) * H_SIZE + ks * 32 + kof);
  }
  int lbl0[4], lbl1[4];
#pragma unroll
  for (int r = 0; r < 4; ++r) {
    int rr = r0 + ((l >> 4) << 2) + r;
    lbl0[r] = tgts[(size_t)(rr & 63) * T_SIZE + (rr >> 6)];
    rr += 16;
    lbl1[r] = tgts[(size_t)(rr & 63) * T_SIZE + (rr >> 6)];
  }

  float sm0[4] = {0.f, 0.f, 0.f, 0.f}, sm1[4] = {0.f, 0.f, 0.f, 0.f};
  float tg0[4] = {0.f, 0.f, 0.f, 0.f}, tg1[4] = {0.f, 0.f, 0.f, 0.f};

  bf16x8 p0[8], p1[8];
  loadB8(p0, Wvb, cbase + ln, 0, kof);
  for (int ct = 0; ct < 64; ++ct) {
    const int vc = cbase + ct * 16 + ln;
    const int vcn = cbase + ((ct < 63) ? ct + 1 : ct) * 16 + ln;
    f32x4 a0 = {0.f, 0.f, 0.f, 0.f};
    f32x4 a1 = {0.f, 0.f, 0.f, 0.f};
    loadB8(p1, Wvb, vc, 1, kof);
#pragma unroll
    for (int ks = 0; ks < 8; ++ks) {
      a0 = __builtin_amdgcn_mfma_f32_16x16x32_bf16(av0[ks], p0[ks], a0, 0, 0, 0);
      a1 = __builtin_amdgcn_mfma_f32_16x16x32_bf16(av1[ks], p0[ks], a1, 0, 0, 0);
    }
    loadB8(p0, Wvb, vcn, 0, kof);
#pragma unroll
    for (int ks = 0; ks < 8; ++ks) {
      a0 = __builtin_amdgcn_mfma_f32_16x16x32_bf16(av0[8 + ks], p1[ks], a0, 0, 0, 0);
      a1 = __builtin_amdgcn_mfma_f32_16x16x32_bf16(av1[8 + ks], p1[ks], a1, 0, 0, 0);
    }
    float bb = bvp[vc];
#pragma unroll
    for (int r = 0; r < 4; ++r) {
      float lg = a0[r] + bb;
      sm0[r] += __expf(lg);
      tg0[r] += (vc == lbl0[r]) ? lg : 0.f;
      float lh = a1[r] + bb;
      sm1[r] += __expf(lh);
      tg1[r] += (vc == lbl1[r]) ? lh : 0.f;
    }
  }

#pragma unroll
  for (int off = 1; off <= 8; off <<= 1) {
#pragma unroll
    for (int r = 0; r < 4; ++r) {
      sm0[r] += __shfl_xor(sm0[r], off, 64);
      tg0[r] += __shfl_xor(tg0[r], off, 64);
      sm1[r] += __shfl_xor(sm1[r], off, 64);
      tg1[r] += __shfl_xor(tg1[r], off, 64);
    }
  }
  if (ln == 0) {
    int rrw = r0 + ((l >> 4) << 2);
#pragma unroll
    for (int r = 0; r < 4; ++r) {
      psm[(size_t)cb * 8192 + rrw + r]      = sm0[r];
      ptg[(size_t)cb * 8192 + rrw + r]      = tg0[r];
      psm[(size_t)cb * 8192 + rrw + 16 + r] = sm1[r];
      ptg[(size_t)cb * 8192 + rrw + 16 + r] = tg1[r];
    }
  }
}

// ---------------- merge 8 col-strip partials, per-row loss, sum ----------------
__global__ __launch_bounds__(256) void cemerge_k(const float* __restrict__ psm,
                                                 const float* __restrict__ ptg,
                                                 float* __restrict__ accum) {
  int g = blockIdx.x * 256 + threadIdx.x;   // 0..8191
  float S = 0.f, T = 0.f;
#pragma unroll
  for (int j = 0; j < 8; ++j) {
    S += psm[(size_t)j * 8192 + g];
    T += ptg[(size_t)j * 8192 + g];
  }
  float loss = logf(S) - T;
#pragma unroll
  for (int off = 32; off >= 1; off >>= 1)
    loss += __shfl_xor(loss, off, 64);
  if ((threadIdx.x & 63) == 0) atomicAdd(accum, loss);
}

__global__ void finish_k(const float* __restrict__ accum, float* __restrict__ out) {
  out[0] = accum[0] * (1.f / (float)(B_SIZE * T_SIZE));
}

// ---------------- launcher ----------------
extern "C" void kernel_launch(void* const* d_in, const int* in_sizes, int n_in,
                              void* d_out, int out_size, void* d_ws, size_t ws_size,
                              hipStream_t stream) {
  const int*   ids  = (const int*)  d_in[0];
  const int*   tgts = (const int*)  d_in[1];
  const float* emb  = (const float*)d_in[2];
  const float* W1   = (const float*)d_in[3];
  const float* b1   = (const float*)d_in[4];
  const float* W2   = (const float*)d_in[5];
  const float* b2   = (const float*)d_in[6];
  const float* Wv   = (const float*)d_in[7];
  const float* bv   = (const float*)d_in[8];
  float* out = (float*)d_out;

  // ws layout (bytes), total ~34.2 MB:
  char* ws = (char*)d_ws;
  unsigned short* xb    = (unsigned short*)(ws);                 //  8,388,608
  unsigned short* outsb = (unsigned short*)(ws + 8388608);       //  8,388,608 (=h2all)
  unsigned short* h1all = (unsigned short*)(ws + 16777216);      //  8,388,608
  unsigned short* Wvb   = (unsigned short*)(ws + 25165824);      //  8,388,608 (padded 8192x512)
  unsigned short* hzero = (unsigned short*)(ws + 33554432);      //     65,536
  float*          bvp   = (float*)         (ws + 33619968);      //     32,768
  float*          accum = (float*)         (ws + 33652736);      //          4 (pad 64)
  float*          psm   = (float*)         (ws + 33652800);      //    262,144
  float*          ptg   = (float*)         (ws + 33914944);      //    262,144

  // zero hzero + bvp + accum (contiguous 98,368 B = 24,592 u32)
  fill_k<<<97, 256, 0, stream>>>((unsigned*)hzero, 0u, 24592);
  // sentinel-fill outsb + h1all (contiguous 16,777,216 B = 4,194,304 u32)
  fill_k<<<16384, 256, 0, stream>>>((unsigned*)outsb, SENT, 4194304);

  bvp_k<<<32, 256, 0, stream>>>(bv, bvp);
  xgather_k<<<2048, 256, 0, stream>>>(ids, emb, xb);
  trans_k<<<1024, 256, 0, stream>>>(Wv, Wvb, V_SIZE, 128, V_SIZE); // padded transpose

  {
    void* args[] = { (void*)&W1, (void*)&W2, (void*)&b1, (void*)&b2,
                     (void*)&xb, (void*)&hzero, (void*)&h1all, (void*)&outsb };
    hipError_t e = hipLaunchCooperativeKernel((const void*)recur_k,
                                              dim3(RBLK), dim3(RTH),
                                              args, 0, stream);
    if (e != hipSuccess) {
      recur_k<<<dim3(RBLK), dim3(RTH), 0, stream>>>(W1, W2, b1, b2, xb, hzero,
                                                    h1all, outsb);
    }
  }

  ce2_k<<<256, 512, 0, stream>>>(outsb, Wvb, bvp, tgts, psm, ptg);
  cemerge_k<<<32, 256, 0, stream>>>(psm, ptg, accum);
  finish_k<<<1, 1, 0, stream>>>(accum, out);
}